// Round 10
// baseline (131.727 us; speedup 1.0000x reference)
//
#include <hip/hip_runtime.h>
#include <math.h>

// PartTripletLoss on MI355X.
// feature [64,512,256] f32, labels structured (class = j/16, 16 per class),
// margin 0.2, num_pos = 16. Outputs: [loss_mean.mean(), nonzero_num.mean()].
//
// R10: pipeline rotation + fused finalize.
//  - Bs is dead during hinge (hinge uses acc/srt regs + sumt only), so the
//    next tile's 32 KB DMA is issued right after MFMA's Bs reads complete
//    and flies during the hinge window (R9 stalled the full DMA latency
//    between back-to-back barriers). Same 2 barriers/tile, same 43 KB LDS
//    (3 blocks/CU).
//  - x2s LDS buffer replaced by 4 regs/lane loaded from L2-resident x2g.
//  - finalize_kernel fused: per-part atomicAdd + done-counter; the 16th
//    block of a part computes lm and atomicAdds into out (convert zeroes
//    accumulators + out; stream order makes that safe).
// Kept: convert_kernel pre-swizzled bf16 + exact norms (R9), DMA staging
// via global_load_lds 16B (R9), j-split grid (NP,8,2) (R7), A-frags in
// VGPRs (R7), sorted-positives hinge (R5), bf16 MFMA 16x16x32 (R4, absmax
// 0.0), XCD co-location p%8 (R6).

#define MARGIN 0.2f
constexpr int NP = 64;   // parts
constexpr int M = 512;   // samples per part
constexpr int D = 256;   // feature dim
constexpr int SDS = 20;  // sortd/sumt row stride (floats)

typedef __attribute__((ext_vector_type(8))) short bf16x8;
typedef __attribute__((ext_vector_type(4))) float f32x4;
typedef __attribute__((address_space(1))) const unsigned int as1_uint;
typedef __attribute__((address_space(3))) unsigned int as3_uint;

__device__ __forceinline__ unsigned f2bf(float x) {  // fp32 -> bf16 RNE bits
  unsigned b = __float_as_uint(x);
  return (b + 0x7FFFu + ((b >> 16) & 1u)) >> 16;
}
__device__ __forceinline__ uint4 pack8u(float4 v0, float4 v1) {
  uint4 p;
  p.x = f2bf(v0.x) | (f2bf(v0.y) << 16);
  p.y = f2bf(v0.z) | (f2bf(v0.w) << 16);
  p.z = f2bf(v1.x) | (f2bf(v1.y) << 16);
  p.w = f2bf(v1.z) | (f2bf(v1.w) << 16);
  return p;
}
__device__ __forceinline__ float sq8(float4 v0, float4 v1) {
  return v0.x * v0.x + v0.y * v0.y + v0.z * v0.z + v0.w * v0.w +
         v1.x * v1.x + v1.y * v1.y + v1.z * v1.z + v1.w * v1.w;
}

// feature f32 -> swizzled bf16 tensor + exact row norms; zero accumulators.
__global__ __launch_bounds__(256) void convert_kernel(
    const float* __restrict__ feat, unsigned short* __restrict__ fb,
    float* __restrict__ x2g, float* __restrict__ psumP,
    float* __restrict__ pcntP, unsigned* __restrict__ donec,
    float* __restrict__ out) {
  const int t = threadIdx.x;
  if (blockIdx.x == 0) {
    if (t < 64) {
      psumP[t] = 0.f;
      pcntP[t] = 0.f;
      donec[t] = 0u;
    }
    if (t == 0) { out[0] = 0.f; out[1] = 0.f; }
  }
  const int R = blockIdx.x * 8 + (t >> 5);  // global row (p*512 + local)
  const int c = t & 31;                     // 16B chunk within row
  const int r = R & 63;                     // row within 64-row tile
  const float* src = feat + (size_t)R * D + c * 8;
  float4 v0 = ((const float4*)src)[0], v1 = ((const float4*)src)[1];
  *(uint4*)&fb[((size_t)R * 32 + (c ^ (r & 7))) * 8] = pack8u(v0, v1);
  float ss = sq8(v0, v1);
  ss += __shfl_xor(ss, 16, 32);
  ss += __shfl_xor(ss, 8, 32);
  ss += __shfl_xor(ss, 4, 32);
  ss += __shfl_xor(ss, 2, 32);
  ss += __shfl_xor(ss, 1, 32);
  if (c == 0) x2g[R] = ss;
}

__global__ __launch_bounds__(256, 2) void triplet_kernel(
    const unsigned short* __restrict__ fb, const float* __restrict__ x2g,
    float* __restrict__ psumP, float* __restrict__ pcntP,
    unsigned* __restrict__ donec, float* __restrict__ out) {
  __shared__ unsigned short Bs[64 * 32 * 8];  // 32 KB: full K=256 j-tile
  __shared__ float sortd[64 * SDS];           // hp -> sorted asc (5 KB)
  __shared__ float sumt[64 * SDS];            // suffix sums (5 KB)
  __shared__ float reds[4], redc[4];

  const int p = blockIdx.x;     // part (lin id % 8 = XCD co-location)
  const int diag = blockIdx.y;  // anchor tile == diagonal j-tile
  const int h = blockIdx.z;     // j-ring half
  const int i0 = diag * 64;
  const int t = threadIdx.x;
  const int w = t >> 6, L = t & 63;
  const int tx = L & 15, quad = L >> 4;
  const int tx7 = tx & 7;
  const float* x2p = x2g + (size_t)p * M;

  auto dma_tile = [&](int j0) {  // 32 KB linear copy, swizzle pre-baked
    const char* gsrc = (const char*)fb + ((size_t)p * M + j0) * 512;
    char* lbase = (char*)Bs + (t >> 6) * 1024;  // wave-uniform
#pragma unroll
    for (int i = 0; i < 8; i++)
      __builtin_amdgcn_global_load_lds((as1_uint*)(gsrc + i * 4096 + t * 16),
                                       (as3_uint*)(lbase + i * 4096), 16, 0, 0);
  };

  dma_tile(i0);  // prologue: tile 0 is the diagonal

  // ---- A fragments from pre-swizzled bf16 tensor (row i0+w*16+tx) ----
  const size_t Ra = (size_t)p * M + i0 + w * 16 + tx;
  bf16x8 af[8];
#pragma unroll
  for (int kc = 0; kc < 2; kc++)
#pragma unroll
    for (int ks = 0; ks < 4; ks++) {
      const int ca = kc * 16 + ks * 4 + quad;
      af[kc * 4 + ks] = *(const bf16x8*)&fb[(Ra * 32 + (ca ^ tx7)) * 8];
    }
  float x2i[4];
#pragma unroll
  for (int r = 0; r < 4; r++) x2i[r] = x2p[i0 + w * 16 + quad * 4 + r];

  f32x4 srt[4][4];
  float hsum = 0.f;
  int hcnt = 0;

  // ti=0 -> tt=0 (diag, both halves, for the sort);
  // h=0 hinges tt {0,1,2,3}; h=1 grams tt0 then hinges tt {4,5,6,7}.
  const int ntiles = 4 + h;
  for (int ti = 0; ti < ntiles; ti++) {
    const int tt = (ti == 0) ? 0 : ti + h * 3;
    const int j0 = ((diag + tt) & 7) * 64;

    __syncthreads();  // drains vmcnt: DMA'd tile now valid in Bs

    float x2j[4];
#pragma unroll
    for (int f = 0; f < 4; f++) x2j[f] = x2p[j0 + f * 16 + tx];

    f32x4 acc[4];
#pragma unroll
    for (int f = 0; f < 4; f++) acc[f] = (f32x4){0.f, 0.f, 0.f, 0.f};
#pragma unroll
    for (int kc = 0; kc < 2; kc++)
#pragma unroll
      for (int ks = 0; ks < 4; ks++) {
        const bf16x8 a = af[kc * 4 + ks];
        const int cb = kc * 16 + ks * 4 + quad;
#pragma unroll
        for (int f = 0; f < 4; f++) {
          const int rowb = f * 16 + tx;
          bf16x8 b = *(bf16x8*)&Bs[(rowb * 32 + (cb ^ tx7)) * 8];
          acc[f] =
              __builtin_amdgcn_mfma_f32_16x16x32_bf16(a, b, acc[f], 0, 0, 0);
        }
      }

    __syncthreads();  // all Bs reads done -> safe to overwrite
    {  // issue next tile's DMA; it flies during hinge (and sort at ti=0)
      const int nti = ti + 1;
      if (nti < ntiles) {
        const int ntt = (nti == 0) ? 0 : nti + h * 3;
        dma_tile(((diag + ntt) & 7) * 64);
      }
    }

    // C layout (m89): lane holds col = tx, rows = quad*4 + r.
    if (ti == 0) {  // diagonal: harvest positives, sort, suffix sums
#pragma unroll
      for (int r = 0; r < 4; r++) {
        float d2 = x2i[r] + x2j[w] - 2.f * acc[w][r];
        sortd[(w * 16 + quad * 4 + r) * SDS + tx] =
            MARGIN + sqrtf(fmaxf(d2, 0.f));
      }
      __syncthreads();
      if (t < 64) {  // per anchor row: bitonic sort 16 + suffix sums
        float v[16];
#pragma unroll
        for (int q4 = 0; q4 < 4; q4++) {
          f32x4 vv = *(f32x4*)&sortd[t * SDS + q4 * 4];
          v[q4 * 4 + 0] = vv.x; v[q4 * 4 + 1] = vv.y;
          v[q4 * 4 + 2] = vv.z; v[q4 * 4 + 3] = vv.w;
        }
#pragma unroll
        for (int k = 2; k <= 16; k <<= 1)
#pragma unroll
          for (int j = k >> 1; j > 0; j >>= 1)
#pragma unroll
            for (int i = 0; i < 16; i++) {
              const int l = i ^ j;
              if (l > i) {
                const bool asc = ((i & k) == 0);
                if (asc ? (v[i] > v[l]) : (v[i] < v[l])) {
                  float tmp = v[i]; v[i] = v[l]; v[l] = tmp;
                }
              }
            }
#pragma unroll
        for (int q4 = 0; q4 < 4; q4++)
          *(f32x4*)&sortd[t * SDS + q4 * 4] =
              (f32x4){v[q4 * 4], v[q4 * 4 + 1], v[q4 * 4 + 2], v[q4 * 4 + 3]};
        float run = 0.f;
        sumt[t * SDS + 0] = 0.f;
#pragma unroll
        for (int c = 1; c <= 16; c++) {
          run += v[16 - c];
          sumt[t * SDS + c] = run;
        }
      }
      __syncthreads();
#pragma unroll
      for (int r = 0; r < 4; r++)
#pragma unroll
        for (int q4 = 0; q4 < 4; q4++)
          srt[r][q4] = *(f32x4*)&sortd[(w * 16 + quad * 4 + r) * SDS + q4 * 4];
    }

    // hinge: rank via 16 compares + suffix-sum lookup
#pragma unroll
    for (int f = 0; f < 4; f++) {
      if (ti == 0 && f == w) continue;  // positive block (only at ti==0)
      if (ti == 0 && h == 1) continue;  // h=1 doesn't hinge the diagonal
#pragma unroll
      for (int r = 0; r < 4; r++) {
        const float dn = sqrtf(fmaxf(x2i[r] + x2j[f] - 2.f * acc[f][r], 0.f));
        int c = 0;
#define CMP(sv) c += ((sv) > dn) ? 1 : 0;
        CMP(srt[r][0].x) CMP(srt[r][0].y) CMP(srt[r][0].z) CMP(srt[r][0].w)
        CMP(srt[r][1].x) CMP(srt[r][1].y) CMP(srt[r][1].z) CMP(srt[r][1].w)
        CMP(srt[r][2].x) CMP(srt[r][2].y) CMP(srt[r][2].z) CMP(srt[r][2].w)
        CMP(srt[r][3].x) CMP(srt[r][3].y) CMP(srt[r][3].z) CMP(srt[r][3].w)
#undef CMP
        hsum += sumt[(w * 16 + quad * 4 + r) * SDS + c];
        hsum = fmaf(-(float)c, dn, hsum);
        hcnt += c;
      }
    }
  }

  // block reduction, then per-part atomic accumulation + last-block finalize
  float cf = (float)hcnt;  // <= 1280 per thread, exact
  for (int off = 32; off > 0; off >>= 1) {
    hsum += __shfl_down(hsum, off, 64);
    cf += __shfl_down(cf, off, 64);
  }
  if (L == 0) { reds[w] = hsum; redc[w] = cf; }
  __syncthreads();
  if (t == 0) {
    const float bs = reds[0] + reds[1] + reds[2] + reds[3];
    const float bc = redc[0] + redc[1] + redc[2] + redc[3];
    atomicAdd(&psumP[p], bs);
    atomicAdd(&pcntP[p], bc);
    __threadfence();  // part sums visible before done-count
    const unsigned done = atomicAdd(&donec[p], 1u);
    if (done == 15u) {  // 16th block of part p: finalize this part
      const float ts = atomicAdd(&psumP[p], 0.f);  // coherent read
      const float tc = atomicAdd(&pcntP[p], 0.f);
      // reference: where(cnt==0, 0, sum / max(cnt, 1)); then mean over parts
      const float lm = (tc == 0.f) ? 0.f : ts / fmaxf(tc, 1.f);
      atomicAdd(&out[0], lm * 0.015625f);   // /64
      atomicAdd(&out[1], tc * 0.015625f);
    }
  }
}

extern "C" void kernel_launch(void* const* d_in, const int* in_sizes, int n_in,
                              void* d_out, int out_size, void* d_ws,
                              size_t ws_size, hipStream_t stream) {
  const float* feat = (const float*)d_in[0];
  float* ws = (float*)d_ws;
  float* psumP = ws;                      // 64 floats
  float* pcntP = ws + 64;                 // 64 floats
  unsigned* donec = (unsigned*)(ws + 128);  // 64 uints
  float* x2g = ws + 192;                  // 32768 floats
  unsigned short* fb = (unsigned short*)(ws + 192 + 32768);  // 16.78 MB bf16
  float* out = (float*)d_out;

  convert_kernel<<<(NP * M) / 8, 256, 0, stream>>>(feat, fb, x2g, psumP,
                                                   pcntP, donec, out);
  dim3 grid(NP, 8, 2);  // lin id % 8 == p % 8 -> part co-located on one XCD
  triplet_kernel<<<grid, 256, 0, stream>>>(fb, x2g, psumP, pcntP, donec, out);
}

// Round 11
// 122.852 us; speedup vs baseline: 1.0722x; 1.0722x over previous
//
#include <hip/hip_runtime.h>
#include <math.h>

// PartTripletLoss on MI355X.
// feature [64,512,256] f32, labels structured (class = j/16, 16 per class),
// margin 0.2, num_pos = 16. Outputs: [loss_mean.mean(), nonzero_num.mean()].
//
// R11 = R9 (proven 48.5 us triplet) + ONE change: pipeline rotation.
// R10 bundled rotation + atomic finalize (__threadfence -> cross-XCD L2
// invalidate per block = L2 thrash) + x2-to-registers, and regressed; the
// fence is the prime suspect. This round isolates the rotation:
//   drain-barrier -> MFMA -> reads-done-barrier -> issue next tile's DMA
//   (+ x2s ping-pong load) -> hinge (covers DMA flight).
// At ti==0 the DMA issue is deferred past the sort barriers (they drain
// vmcnt(0) and would void the overlap). Finalize back to its own kernel;
// x2s back in LDS (2x64 ping-pong).
// Kept: convert_kernel pre-swizzled bf16 + exact norms (R9), global_load_lds
// 16B DMA (R9), j-split grid (NP,8,2) (R7), A-frags in VGPRs (R7),
// sorted-positives hinge (R5), bf16 MFMA 16x16x32 (R4, absmax 0.0),
// XCD co-location p%8 (R6).

#define MARGIN 0.2f
constexpr int NP = 64;   // parts
constexpr int M = 512;   // samples per part
constexpr int D = 256;   // feature dim
constexpr int SDS = 20;  // sortd/sumt row stride (floats)

typedef __attribute__((ext_vector_type(8))) short bf16x8;
typedef __attribute__((ext_vector_type(4))) float f32x4;
typedef __attribute__((address_space(1))) const unsigned int as1_uint;
typedef __attribute__((address_space(3))) unsigned int as3_uint;

__device__ __forceinline__ unsigned f2bf(float x) {  // fp32 -> bf16 RNE bits
  unsigned b = __float_as_uint(x);
  return (b + 0x7FFFu + ((b >> 16) & 1u)) >> 16;
}
__device__ __forceinline__ uint4 pack8u(float4 v0, float4 v1) {
  uint4 p;
  p.x = f2bf(v0.x) | (f2bf(v0.y) << 16);
  p.y = f2bf(v0.z) | (f2bf(v0.w) << 16);
  p.z = f2bf(v1.x) | (f2bf(v1.y) << 16);
  p.w = f2bf(v1.z) | (f2bf(v1.w) << 16);
  return p;
}
__device__ __forceinline__ float sq8(float4 v0, float4 v1) {
  return v0.x * v0.x + v0.y * v0.y + v0.z * v0.z + v0.w * v0.w +
         v1.x * v1.x + v1.y * v1.y + v1.z * v1.z + v1.w * v1.w;
}

// feature f32 -> swizzled bf16 tensor + exact row norms. 8 rows/block.
__global__ __launch_bounds__(256) void convert_kernel(
    const float* __restrict__ feat, unsigned short* __restrict__ fb,
    float* __restrict__ x2g) {
  const int t = threadIdx.x;
  const int R = blockIdx.x * 8 + (t >> 5);  // global row (p*512 + local)
  const int c = t & 31;                     // 16B chunk within row
  const int r = R & 63;                     // row within 64-row tile
  const float* src = feat + (size_t)R * D + c * 8;
  float4 v0 = ((const float4*)src)[0], v1 = ((const float4*)src)[1];
  *(uint4*)&fb[((size_t)R * 32 + (c ^ (r & 7))) * 8] = pack8u(v0, v1);
  float ss = sq8(v0, v1);
  ss += __shfl_xor(ss, 16, 32);
  ss += __shfl_xor(ss, 8, 32);
  ss += __shfl_xor(ss, 4, 32);
  ss += __shfl_xor(ss, 2, 32);
  ss += __shfl_xor(ss, 1, 32);
  if (c == 0) x2g[R] = ss;
}

__global__ __launch_bounds__(256, 2) void triplet_kernel(
    const unsigned short* __restrict__ fb, const float* __restrict__ x2g,
    float* __restrict__ psum, float* __restrict__ pcnt) {
  __shared__ unsigned short Bs[64 * 32 * 8];  // 32 KB: full K=256 j-tile
  __shared__ float sortd[64 * SDS];           // hp -> sorted asc (5 KB)
  __shared__ float sumt[64 * SDS];            // suffix sums (5 KB)
  __shared__ float x2s[2][64];                // ping-pong tile row norms
  __shared__ float reds[4], redc[4];

  const int p = blockIdx.x;     // part (lin id % 8 = XCD co-location)
  const int diag = blockIdx.y;  // anchor tile == diagonal j-tile
  const int h = blockIdx.z;     // j-ring half
  const int i0 = diag * 64;
  const int t = threadIdx.x;
  const int w = t >> 6, L = t & 63;
  const int tx = L & 15, quad = L >> 4;
  const int tx7 = tx & 7;
  const float* x2p = x2g + (size_t)p * M;

  auto dma_tile = [&](int j0) {  // 32 KB linear copy, swizzle pre-baked
    const char* gsrc = (const char*)fb + ((size_t)p * M + j0) * 512;
    char* lbase = (char*)Bs + (t >> 6) * 1024;  // wave-uniform
#pragma unroll
    for (int i = 0; i < 8; i++)
      __builtin_amdgcn_global_load_lds((as1_uint*)(gsrc + i * 4096 + t * 16),
                                       (as3_uint*)(lbase + i * 4096), 16, 0, 0);
  };

  dma_tile(i0);  // prologue: tile 0 is the diagonal
  if (t < 64) x2s[0][t] = x2p[i0 + t];

  // ---- A fragments from pre-swizzled bf16 tensor (row i0+w*16+tx) ----
  const size_t Ra = (size_t)p * M + i0 + w * 16 + tx;
  bf16x8 af[8];
#pragma unroll
  for (int kc = 0; kc < 2; kc++)
#pragma unroll
    for (int ks = 0; ks < 4; ks++) {
      const int ca = kc * 16 + ks * 4 + quad;
      af[kc * 4 + ks] = *(const bf16x8*)&fb[(Ra * 32 + (ca ^ tx7)) * 8];
    }
  float x2i[4];
#pragma unroll
  for (int r = 0; r < 4; r++) x2i[r] = x2p[i0 + w * 16 + quad * 4 + r];

  f32x4 srt[4][4];
  float hsum = 0.f;
  int hcnt = 0;

  // ti=0 -> tt=0 (diag, both halves, for the sort);
  // h=0 hinges tt {0,1,2,3}; h=1 grams tt0 then hinges tt {4,5,6,7}.
  const int ntiles = 4 + h;
  for (int ti = 0; ti < ntiles; ti++) {
    const int cur = ti & 1;
    __syncthreads();  // drains vmcnt: DMA'd tile + x2s[cur] now valid

    f32x4 acc[4];
#pragma unroll
    for (int f = 0; f < 4; f++) acc[f] = (f32x4){0.f, 0.f, 0.f, 0.f};
#pragma unroll
    for (int kc = 0; kc < 2; kc++)
#pragma unroll
      for (int ks = 0; ks < 4; ks++) {
        const bf16x8 a = af[kc * 4 + ks];
        const int cb = kc * 16 + ks * 4 + quad;
#pragma unroll
        for (int f = 0; f < 4; f++) {
          const int rowb = f * 16 + tx;
          bf16x8 b = *(bf16x8*)&Bs[(rowb * 32 + (cb ^ tx7)) * 8];
          acc[f] =
              __builtin_amdgcn_mfma_f32_16x16x32_bf16(a, b, acc[f], 0, 0, 0);
        }
      }

    __syncthreads();  // all Bs reads done -> safe to overwrite

    const int nti = ti + 1;
    const bool havenext = nti < ntiles;
    const int nj0 = havenext ? (((diag + nti + h * 3) & 7) * 64) : 0;
    if (ti != 0 && havenext) {  // issue next DMA; flies during hinge
      dma_tile(nj0);
      if (t < 64) x2s[nti & 1][t] = x2p[nj0 + t];
    }

    // C layout (m89): lane holds col = tx, rows = quad*4 + r.
    if (ti == 0) {  // diagonal: harvest positives, sort, suffix sums
      const float xj = x2s[0][w * 16 + tx];
#pragma unroll
      for (int r = 0; r < 4; r++) {
        float d2 = x2i[r] + xj - 2.f * acc[w][r];
        sortd[(w * 16 + quad * 4 + r) * SDS + tx] =
            MARGIN + sqrtf(fmaxf(d2, 0.f));
      }
      __syncthreads();
      if (t < 64) {  // per anchor row: bitonic sort 16 + suffix sums
        float v[16];
#pragma unroll
        for (int q4 = 0; q4 < 4; q4++) {
          f32x4 vv = *(f32x4*)&sortd[t * SDS + q4 * 4];
          v[q4 * 4 + 0] = vv.x; v[q4 * 4 + 1] = vv.y;
          v[q4 * 4 + 2] = vv.z; v[q4 * 4 + 3] = vv.w;
        }
#pragma unroll
        for (int k = 2; k <= 16; k <<= 1)
#pragma unroll
          for (int j = k >> 1; j > 0; j >>= 1)
#pragma unroll
            for (int i = 0; i < 16; i++) {
              const int l = i ^ j;
              if (l > i) {
                const bool asc = ((i & k) == 0);
                if (asc ? (v[i] > v[l]) : (v[i] < v[l])) {
                  float tmp = v[i]; v[i] = v[l]; v[l] = tmp;
                }
              }
            }
#pragma unroll
        for (int q4 = 0; q4 < 4; q4++)
          *(f32x4*)&sortd[t * SDS + q4 * 4] =
              (f32x4){v[q4 * 4], v[q4 * 4 + 1], v[q4 * 4 + 2], v[q4 * 4 + 3]};
        float run = 0.f;
        sumt[t * SDS + 0] = 0.f;
#pragma unroll
        for (int c = 1; c <= 16; c++) {
          run += v[16 - c];
          sumt[t * SDS + c] = run;
        }
      }
      __syncthreads();
#pragma unroll
      for (int r = 0; r < 4; r++)
#pragma unroll
        for (int q4 = 0; q4 < 4; q4++)
          srt[r][q4] = *(f32x4*)&sortd[(w * 16 + quad * 4 + r) * SDS + q4 * 4];

      if (havenext) {  // DMA deferred past sort barriers (they drain vmcnt)
        dma_tile(nj0);
        if (t < 64) x2s[nti & 1][t] = x2p[nj0 + t];
      }

      if (h == 0) {  // hinge diagonal tile's negative frags
#pragma unroll
        for (int f = 0; f < 4; f++) {
          if (f == w) continue;  // positive block
          const float xj2 = x2s[0][f * 16 + tx];
#pragma unroll
          for (int r = 0; r < 4; r++) {
            const float dn = sqrtf(fmaxf(x2i[r] + xj2 - 2.f * acc[f][r], 0.f));
            int c = 0;
#define CMP(sv) c += ((sv) > dn) ? 1 : 0;
            CMP(srt[r][0].x) CMP(srt[r][0].y) CMP(srt[r][0].z) CMP(srt[r][0].w)
            CMP(srt[r][1].x) CMP(srt[r][1].y) CMP(srt[r][1].z) CMP(srt[r][1].w)
            CMP(srt[r][2].x) CMP(srt[r][2].y) CMP(srt[r][2].z) CMP(srt[r][2].w)
            CMP(srt[r][3].x) CMP(srt[r][3].y) CMP(srt[r][3].z) CMP(srt[r][3].w)
#undef CMP
            hsum += sumt[(w * 16 + quad * 4 + r) * SDS + c];
            hsum = fmaf(-(float)c, dn, hsum);
            hcnt += c;
          }
        }
      }
    } else {  // off-diagonal: all 16 frags are negatives
#pragma unroll
      for (int f = 0; f < 4; f++) {
        const float xj = x2s[cur][f * 16 + tx];
#pragma unroll
        for (int r = 0; r < 4; r++) {
          const float dn = sqrtf(fmaxf(x2i[r] + xj - 2.f * acc[f][r], 0.f));
          int c = 0;
#define CMP(sv) c += ((sv) > dn) ? 1 : 0;
          CMP(srt[r][0].x) CMP(srt[r][0].y) CMP(srt[r][0].z) CMP(srt[r][0].w)
          CMP(srt[r][1].x) CMP(srt[r][1].y) CMP(srt[r][1].z) CMP(srt[r][1].w)
          CMP(srt[r][2].x) CMP(srt[r][2].y) CMP(srt[r][2].z) CMP(srt[r][2].w)
          CMP(srt[r][3].x) CMP(srt[r][3].y) CMP(srt[r][3].z) CMP(srt[r][3].w)
#undef CMP
          hsum += sumt[(w * 16 + quad * 4 + r) * SDS + c];
          hsum = fmaf(-(float)c, dn, hsum);
          hcnt += c;
        }
      }
    }
  }

  // block reduction
  float cf = (float)hcnt;  // <= 1280 per thread, exact
  for (int off = 32; off > 0; off >>= 1) {
    hsum += __shfl_down(hsum, off, 64);
    cf += __shfl_down(cf, off, 64);
  }
  if (L == 0) { reds[w] = hsum; redc[w] = cf; }
  __syncthreads();
  if (t == 0) {
    psum[p * 16 + diag * 2 + h] = reds[0] + reds[1] + reds[2] + reds[3];
    pcnt[p * 16 + diag * 2 + h] = redc[0] + redc[1] + redc[2] + redc[3];
  }
}

__global__ __launch_bounds__(64) void finalize_kernel(
    const float* __restrict__ psum, const float* __restrict__ pcnt,
    float* __restrict__ out) {
  const int p = threadIdx.x;
  float s = 0.f, c = 0.f;
#pragma unroll
  for (int i = 0; i < 16; i++) {
    s += psum[p * 16 + i];
    c += pcnt[p * 16 + i];
  }
  float lm = (c == 0.f) ? 0.f : s / fmaxf(c, 1.f);
  float ctot = c;
  for (int off = 32; off > 0; off >>= 1) {
    lm += __shfl_down(lm, off, 64);
    ctot += __shfl_down(ctot, off, 64);
  }
  if (p == 0) {
    out[0] = lm / 64.f;
    out[1] = ctot / 64.f;
  }
}

extern "C" void kernel_launch(void* const* d_in, const int* in_sizes, int n_in,
                              void* d_out, int out_size, void* d_ws,
                              size_t ws_size, hipStream_t stream) {
  const float* feat = (const float*)d_in[0];
  float* ws = (float*)d_ws;
  float* psum = ws;           // 1024 floats
  float* pcnt = ws + 1024;    // 1024 floats
  float* x2g = ws + 2048;     // 32768 floats
  unsigned short* fb = (unsigned short*)(ws + 2048 + 32768);  // 16.78 MB bf16
  float* out = (float*)d_out;

  convert_kernel<<<(NP * M) / 8, 256, 0, stream>>>(feat, fb, x2g);
  dim3 grid(NP, 8, 2);  // lin id % 8 == p % 8 -> part co-located on one XCD
  triplet_kernel<<<grid, 256, 0, stream>>>(fb, x2g, psum, pcnt);
  finalize_kernel<<<1, 64, 0, stream>>>(psum, pcnt, out);
}